// Round 6
// baseline (295.407 us; speedup 1.0000x reference)
//
#include <hip/hip_runtime.h>
#include <cstdint>
#include <cstddef>

typedef __bf16 bf16x8 __attribute__((ext_vector_type(8)));
typedef float f32x4 __attribute__((ext_vector_type(4)));
typedef unsigned short u16;
typedef unsigned int u32;

static constexpr int T = 2048;
static constexpr int DM = 1024;
// 1/(32*ln2) = log2(e)/32 : folded into W_Q so attention needs only exp2
static constexpr float QSCALE = 0.04508422f;

#define GLOBAL_AS __attribute__((address_space(1)))
#define LDS_AS __attribute__((address_space(3)))

__device__ __forceinline__ void gld_lds16(const u16* g, u16* l) {
  __builtin_amdgcn_global_load_lds((const GLOBAL_AS u32*)g, (LDS_AS u32*)l, 16, 0, 0);
}

__device__ __forceinline__ u16 f2bf(float f) {
  u32 u = __builtin_bit_cast(u32, f);
  u += 0x7fffu + ((u >> 16) & 1u);
  return (u16)(u >> 16);
}

// pack two fp32 -> 2 bf16 in one dword
__device__ __forceinline__ u32 pkb(float lo, float hi) {
#if __has_builtin(__builtin_amdgcn_cvt_pk_bf16_f32)
  typedef __bf16 bf16x2 __attribute__((ext_vector_type(2)));
  bf16x2 r = __builtin_amdgcn_cvt_pk_bf16_f32(lo, hi);
  return __builtin_bit_cast(u32, r);
#else
  return __builtin_amdgcn_perm(__builtin_bit_cast(u32, hi),
                               __builtin_bit_cast(u32, lo), 0x07060302u);
#endif
}

__device__ __forceinline__ float fexp2(float x) {
#if __has_builtin(__builtin_amdgcn_exp2f)
  return __builtin_amdgcn_exp2f(x);
#else
  return __builtin_exp2f(x);
#endif
}

// gfx950 cross-lane swaps: odd 16-rows of a <-> even 16-rows of b (16-swap);
// upper 32 lanes of a <-> lower 32 lanes of b (32-swap). Each implements a 2x2
// transpose between one lane bit (4 or 5) and the a/b register-index bit.
__device__ __forceinline__ void pl16swap(u32& a, u32& b) {
  asm("v_permlane16_swap_b32 %0, %1" : "+v"(a), "+v"(b));
}
__device__ __forceinline__ void pl32swap(u32& a, u32& b) {
  asm("v_permlane32_swap_b32 %0, %1" : "+v"(a), "+v"(b));
}

// ---------------- Merged prep: X fp32->bf16 convert + weight transpose/convert --------
// One launch instead of two. Block-uniform branch:
//   bid < 12288 : xcvt slice (4096 blocks x 3 tensors)
//   bid >= 12288: wt tile (16 x 16 x 3)
__global__ __launch_bounds__(256) void prep(
    const float* __restrict__ q, const float* __restrict__ k, const float* __restrict__ v,
    u16* __restrict__ oq, u16* __restrict__ ok, u16* __restrict__ ov,
    const float* __restrict__ W0, const float* __restrict__ W1, const float* __restrict__ W2,
    u16* __restrict__ O0, u16* __restrict__ O1, u16* __restrict__ O2) {
  const int bid = blockIdx.x;
  if (bid < 12288) {
    const int zz = bid >> 12;            // /4096
    const int bx = bid & 4095;
    const float* X = zz == 0 ? q : zz == 1 ? k : v;
    u16* O = zz == 0 ? oq : zz == 1 ? ok : ov;
    const size_t i = ((size_t)bx * 256 + threadIdx.x) * 8;
    float4 a0 = *(const float4*)(X + i), a1 = *(const float4*)(X + i + 4);
    uint4 p;
    p.x = pkb(a0.x, a0.y); p.y = pkb(a0.z, a0.w);
    p.z = pkb(a1.x, a1.y); p.w = pkb(a1.z, a1.w);
    *(uint4*)(O + i) = p;
  } else {
    const int t = bid - 12288;
    const int zz = t >> 8;
    const int rem = t & 255;
    const int k0 = (rem & 15) * 64, n0 = (rem >> 4) * 64;
    const float* W = zz == 0 ? W0 : zz == 1 ? W1 : W2;
    u16* O = zz == 0 ? O0 : zz == 1 ? O1 : O2;
    const float sc = zz == 0 ? QSCALE : 1.0f;
    __shared__ float tile[64][68];
    const int tid = threadIdx.x;
#pragma unroll
    for (int it = 0; it < 4; ++it) {
      int chunk = tid + it * 256;
      int r = chunk >> 4, c4 = (chunk & 15) * 4;
      *(float4*)&tile[r][c4] = *(const float4*)(W + (size_t)(k0 + r) * DM + n0 + c4);
    }
    __syncthreads();
#pragma unroll
    for (int it = 0; it < 4; ++it) {
      int chunk = tid + it * 256;
      int n = chunk >> 4, k4 = (chunk & 15) * 4;
      ushort4 o;
      o.x = f2bf(tile[k4 + 0][n] * sc);
      o.y = f2bf(tile[k4 + 1][n] * sc);
      o.z = f2bf(tile[k4 + 2][n] * sc);
      o.w = f2bf(tile[k4 + 3][n] * sc);
      *(ushort4*)(O + (size_t)(n0 + n) * DM + k0 + k4) = o;
    }
  }
}

// ---------------- Projection GEMM: BK=64, XCD-stripe swizzle, fused V-transpose -------
// REVERTED to (256,3): round-5's (256,4) coincided with a ~12.7us regression in the
// non-flash pool; live set (acc 64 + frags 32 + 8 in-flight gld addrs) ~125-130 VGPR
// likely spilled under the 128 cap. Do not raise the occupancy bound on this kernel.
__global__ __launch_bounds__(256, 3) void gemm_proj(
    const u16* __restrict__ Xq, const u16* __restrict__ Xk, const u16* __restrict__ Xv,
    const u16* __restrict__ Wq, const u16* __restrict__ Wk, const u16* __restrict__ Wv,
    u16* __restrict__ Oq, u16* __restrict__ Ok, u16* __restrict__ VHt) {
  const int z = blockIdx.y;
  const u16* X = z == 0 ? Xq : z == 1 ? Xk : Xv;    // [M][K] bf16
  const u16* Wt = z == 0 ? Wq : z == 1 ? Wk : Wv;   // [N][K] bf16
  const int xcd = blockIdx.x & 7, j = blockIdx.x >> 3;
  const int n0 = (j & 7) * 128;
  const int m0 = (xcd * 8 + (j >> 3)) * 128;
  __shared__ u16 Al[128][64];   // unpadded; chunk c of row r stored at c^(r&7)
  __shared__ u16 Bl[128][64];
  const int tid = threadIdx.x, w = tid >> 6, lane = tid & 63;
  const int c16 = lane & 15, quad = lane >> 4;
  const int wm = (w >> 1) * 64, wn = (w & 1) * 64;
  const int rk = lane >> 3;                    // row-in-8 for DMA
  const int ck = ((lane & 7) ^ rk) * 8;        // swizzled global chunk
  const int swz = c16 & 7;
  f32x4 acc[4][4] = {};
  const u16* ga = X + (size_t)(m0 + w * 32 + rk) * DM + ck;
  const u16* gb = Wt + (size_t)(n0 + w * 32 + rk) * DM + ck;
  for (int kk = 0; kk < 1024; kk += 64) {
    __syncthreads();
#pragma unroll
    for (int i = 0; i < 4; ++i) {
      gld_lds16(ga + kk + (size_t)(i * 8) * DM, &Al[w * 32 + i * 8][0]);
      gld_lds16(gb + kk + (size_t)(i * 8) * DM, &Bl[w * 32 + i * 8][0]);
    }
    __syncthreads();
#pragma unroll
    for (int s = 0; s < 2; ++s) {
      bf16x8 af[4], bfr[4];
#pragma unroll
      for (int t = 0; t < 4; ++t) af[t] = *(const bf16x8*)&Al[wm + t * 16 + c16][((quad + 4 * s) ^ swz) * 8];
#pragma unroll
      for (int t = 0; t < 4; ++t) bfr[t] = *(const bf16x8*)&Bl[wn + t * 16 + c16][((quad + 4 * s) ^ swz) * 8];
#pragma unroll
      for (int mt = 0; mt < 4; ++mt)
#pragma unroll
        for (int nt = 0; nt < 4; ++nt)
          acc[mt][nt] = __builtin_amdgcn_mfma_f32_16x16x32_bf16(af[mt], bfr[nt], acc[mt][nt], 0, 0, 0);
    }
  }
  if (z < 2) {
    u16* O = z == 0 ? Oq : Ok;
#pragma unroll
    for (int mt = 0; mt < 4; ++mt)
#pragma unroll
      for (int nt = 0; nt < 4; ++nt)
#pragma unroll
        for (int r = 0; r < 4; ++r) {
          size_t row = m0 + wm + mt * 16 + quad * 4 + r;
          size_t col = n0 + wn + nt * 16 + c16;
          O[row * DM + col] = f2bf(acc[mt][nt][r]);
        }
  } else {
    // V slice: write transposed VHt[bh][d][t]; the 4 r-values are consecutive t.
#pragma unroll
    for (int mt = 0; mt < 4; ++mt)
#pragma unroll
      for (int nt = 0; nt < 4; ++nt) {
        const int row0 = m0 + wm + mt * 16 + quad * 4;
        const int col = n0 + wn + nt * 16 + c16;
        const int bb = row0 >> 11, t0 = row0 & 2047;
        const int hh = col >> 6, dd = col & 63;
        ushort4 o;
        o.x = f2bf(acc[mt][nt][0]);
        o.y = f2bf(acc[mt][nt][1]);
        o.z = f2bf(acc[mt][nt][2]);
        o.w = f2bf(acc[mt][nt][3]);
        *(ushort4*)(VHt + ((size_t)((bb * 16 + hh) * 64 + dd)) * T + t0) = o;
      }
  }
}

// ---------------- Flash attention + residual, S^T form, permlane P-exchange ----------
// NO setprio anywhere (rounds 2/3: priority asymmetry desyncs the qb-cohort -> K/V
// falls out of L2, FETCH 52->167MB). v8 ones-MFMA denominators (round 5: -6.2us).
// This round: launched as TWO 512-block dispatches (qoff 0/8) so gemm_proj surfaces
// in the rocprof top-5 — observability for the gemm decision, ~+3-8us expected cost.
__global__ __launch_bounds__(256, 4) void flash_kernel(
    const u16* __restrict__ QH, const u16* __restrict__ KH, const u16* __restrict__ VHt,
    const float* __restrict__ res, float* __restrict__ out, const int qoff) {
  const int blk = blockIdx.x;
  const int x = blk & 7, g = blk >> 3;
  const int bh = x * 8 + (g & 7);          // XCD x owns heads 8x..8x+7 (K/V ~4MB = L2)
  const int qb = (g >> 3) + qoff;          // 0..15 across the two dispatches
  const int b = bh >> 4, h = bh & 15;
  const int tid = threadIdx.x, w = tid >> 6, lane = tid & 63;
  const int c16 = lane & 15, quad = lane >> 4;
  const int swzq = c16 & 7;
  __shared__ u16 Kl[2][64][64];            // [buf][k][d], chunk c of row r at c^(r&7)
  __shared__ u16 Vt[2][64][64];            // [buf][d][k], same swizzle
  const int qbase = qb * 128 + w * 32;
  bf16x8 bq[2][2];                         // B-frags of Q (resident)
#pragma unroll
  for (int qi = 0; qi < 2; ++qi) {
    const u16* qp = QH + (size_t)(b * T + qbase + qi * 16 + c16) * DM + h * 64 + quad * 8;
    bq[qi][0] = *(const bf16x8*)qp;
    bq[qi][1] = *(const bf16x8*)(qp + 32);
  }
  f32x4 acc[2][4] = {};                    // [qi][nt]
  f32x4 accl[2] = {};                      // softmax denominators (ones-trick)
  const u32 one2 = 0x3F803F80u;            // two bf16 1.0
  const uint4 onev = {one2, one2, one2, one2};
  const bf16x8 vone = __builtin_bit_cast(bf16x8, onev);
  const int rk = lane >> 3;
  const int ck8 = ((lane & 7) ^ rk) * 8;
  const u16* kg = KH + (size_t)(b * T) * DM + h * 64 + ck8;
  const u16* vg = VHt + ((size_t)bh * 64 + w * 16 + rk) * T + ck8;
  // prologue: stage tile 0 into buf 0 (4 outstanding vmem per wave)
  {
    const u16* kg0 = kg + (size_t)(w * 16 + rk) * DM;
    gld_lds16(kg0, &Kl[0][w * 16][0]);
    gld_lds16(kg0 + (size_t)8 * DM, &Kl[0][w * 16 + 8][0]);
    gld_lds16(vg, &Vt[0][w * 16][0]);
    gld_lds16(vg + 8 * T, &Vt[0][w * 16 + 8][0]);
  }
  int cur = 0;
  for (int kt = 0; kt < 32; ++kt) {
    // B1: everyone finished reading buf[cur^1] (their ds_reads were MFMA-consumed)
    __builtin_amdgcn_s_barrier();
    if (kt < 31) {
      const u16* kg0 = kg + (size_t)((kt + 1) * 64 + w * 16 + rk) * DM;
      gld_lds16(kg0, &Kl[cur ^ 1][w * 16][0]);
      gld_lds16(kg0 + (size_t)8 * DM, &Kl[cur ^ 1][w * 16 + 8][0]);
      const u16* vg0 = vg + (kt + 1) * 64;
      gld_lds16(vg0, &Vt[cur ^ 1][w * 16][0]);
      gld_lds16(vg0 + (size_t)8 * T, &Vt[cur ^ 1][w * 16 + 8][0]);
      asm volatile("s_waitcnt vmcnt(4)" ::: "memory");  // tile kt landed; kt+1 in flight
    } else {
      asm volatile("s_waitcnt vmcnt(0)" ::: "memory");  // final tile: drain
    }
    // B2: all waves' buf[cur] stages visible
    __builtin_amdgcn_s_barrier();
    // ---- Phase A: S^T = K Q^T, exp2, permlane quad-exchange -> PV A-frags ----
    bf16x8 ap[2][2];
    {
      bf16x8 ak[4][2];
#pragma unroll
      for (int mt = 0; mt < 4; ++mt) {
        const int r = mt * 16 + c16;
        ak[mt][0] = *(const bf16x8*)&Kl[cur][r][(quad ^ swzq) * 8];
        ak[mt][1] = *(const bf16x8*)&Kl[cur][r][((4 + quad) ^ swzq) * 8];
      }
#pragma unroll
      for (int qi = 0; qi < 2; ++qi) {
        u32 d[2][2][2];                    // [mt1][mt0][jd], all indices static
#pragma unroll
        for (int mt = 0; mt < 4; ++mt) {
          f32x4 st = {};
          st = __builtin_amdgcn_mfma_f32_16x16x32_bf16(ak[mt][0], bq[qi][0], st, 0, 0, 0);
          st = __builtin_amdgcn_mfma_f32_16x16x32_bf16(ak[mt][1], bq[qi][1], st, 0, 0, 0);
          const float p0 = fexp2(st[0]), p1 = fexp2(st[1]);
          const float p2 = fexp2(st[2]), p3 = fexp2(st[3]);
          d[mt >> 1][mt & 1][0] = pkb(p0, p1);
          d[mt >> 1][mt & 1][1] = pkb(p2, p3);
        }
        // transpose (lane bit5 <-> reg bit mt0)
        pl32swap(d[0][0][0], d[0][1][0]);
        pl32swap(d[0][0][1], d[0][1][1]);
        pl32swap(d[1][0][0], d[1][1][0]);
        pl32swap(d[1][0][1], d[1][1][1]);
        // transpose (lane bit4 <-> reg bit mt0)
        pl16swap(d[0][0][0], d[0][1][0]);
        pl16swap(d[0][0][1], d[0][1][1]);
        pl16swap(d[1][0][0], d[1][1][0]);
        pl16swap(d[1][0][1], d[1][1][1]);
        // now d[h][e][jd] holds k = 32h + quad*8 + 4e + 2jd (+0,1) for q=qi*16+c16
        uint4 a0 = {d[0][0][0], d[0][0][1], d[0][1][0], d[0][1][1]};
        uint4 a1 = {d[1][0][0], d[1][0][1], d[1][1][0], d[1][1][1]};
        ap[qi][0] = __builtin_bit_cast(bf16x8, a0);
        ap[qi][1] = __builtin_bit_cast(bf16x8, a1);
      }
    }
    // ---- Phase B: O += P V ; denominators += P . 1 (ones-B-frag MFMA) ----
#pragma unroll
    for (int nt = 0; nt < 4; ++nt) {
      const int r = nt * 16 + c16;
      const bf16x8 bv0 = *(const bf16x8*)&Vt[cur][r][(quad ^ swzq) * 8];
      const bf16x8 bv1 = *(const bf16x8*)&Vt[cur][r][((4 + quad) ^ swzq) * 8];
#pragma unroll
      for (int qi = 0; qi < 2; ++qi) {
        acc[qi][nt] = __builtin_amdgcn_mfma_f32_16x16x32_bf16(ap[qi][0], bv0, acc[qi][nt], 0, 0, 0);
        acc[qi][nt] = __builtin_amdgcn_mfma_f32_16x16x32_bf16(ap[qi][1], bv1, acc[qi][nt], 0, 0, 0);
      }
    }
#pragma unroll
    for (int qi = 0; qi < 2; ++qi) {
      accl[qi] = __builtin_amdgcn_mfma_f32_16x16x32_bf16(ap[qi][0], vone, accl[qi], 0, 0, 0);
      accl[qi] = __builtin_amdgcn_mfma_f32_16x16x32_bf16(ap[qi][1], vone, accl[qi], 0, 0, 0);
    }
    cur ^= 1;
  }
  // epilogue: accl[qi][r] = sum_k P[q][k] for q = qbase + qi*16 + quad*4 + r (all c16)
#pragma unroll
  for (int qi = 0; qi < 2; ++qi) {
#pragma unroll
    for (int r = 0; r < 4; ++r) {
      const float inv = 1.0f / accl[qi][r];
      const size_t rowbase = (size_t)(b * T + qbase + qi * 16 + quad * 4 + r) * DM + h * 64;
#pragma unroll
      for (int nt = 0; nt < 4; ++nt) {
        const size_t idx = rowbase + nt * 16 + c16;
        out[idx] = acc[qi][nt][r] * inv + res[idx];
      }
    }
  }
}

extern "C" void kernel_launch(void* const* d_in, const int* in_sizes, int n_in,
                              void* d_out, int out_size, void* d_ws, size_t ws_size,
                              hipStream_t stream) {
  const float* q = (const float*)d_in[0];
  const float* k = (const float*)d_in[1];
  const float* v = (const float*)d_in[2];
  const float* WQ = (const float*)d_in[3];
  const float* WK = (const float*)d_in[4];
  const float* WV = (const float*)d_in[5];
  char* ws = (char*)d_ws;
  const size_t PH = (size_t)8192 * 1024 * 2;   // bf16 activation buffer bytes
  const size_t WT = (size_t)1024 * 1024 * 2;
  // d_out doubles as scratch for 2 of the 3 bf16 X tensors (fully rewritten by flash).
  u16* XqB = (u16*)d_out;
  u16* XkB = (u16*)d_out + (size_t)8192 * 1024;
  u16* XvB = (u16*)(ws);
  u16* WtQ = (u16*)(ws + PH);
  u16* WtK = (u16*)(ws + PH + WT);
  u16* WtV = (u16*)(ws + PH + 2 * WT);
  u16* QH  = (u16*)(ws + PH + 3 * WT);
  u16* KH  = (u16*)(ws + 2 * PH + 3 * WT);
  u16* VHt = (u16*)(ws + 3 * PH + 3 * WT);

  prep<<<dim3(13056), 256, 0, stream>>>(q, k, v, XqB, XkB, XvB,
                                        WQ, WK, WV, WtQ, WtK, WtV);
  gemm_proj<<<dim3(512, 3), 256, 0, stream>>>(XqB, XkB, XvB, WtQ, WtK, WtV, QH, KH, VHt);
  flash_kernel<<<512, 256, 0, stream>>>(QH, KH, VHt, q, (float*)d_out, 0);
  flash_kernel<<<512, 256, 0, stream>>>(QH, KH, VHt, q, (float*)d_out, 8);
}

// Round 7
// 288.664 us; speedup vs baseline: 1.0234x; 1.0234x over previous
//
#include <hip/hip_runtime.h>
#include <cstdint>
#include <cstddef>

typedef __bf16 bf16x8 __attribute__((ext_vector_type(8)));
typedef float f32x4 __attribute__((ext_vector_type(4)));
typedef unsigned short u16;
typedef unsigned int u32;

static constexpr int T = 2048;
static constexpr int DM = 1024;
// 1/(32*ln2) = log2(e)/32 : folded into W_Q so attention needs only exp2
static constexpr float QSCALE = 0.04508422f;

#define GLOBAL_AS __attribute__((address_space(1)))
#define LDS_AS __attribute__((address_space(3)))

__device__ __forceinline__ void gld_lds16(const u16* g, u16* l) {
  __builtin_amdgcn_global_load_lds((const GLOBAL_AS u32*)g, (LDS_AS u32*)l, 16, 0, 0);
}

__device__ __forceinline__ u16 f2bf(float f) {
  u32 u = __builtin_bit_cast(u32, f);
  u += 0x7fffu + ((u >> 16) & 1u);
  return (u16)(u >> 16);
}

// pack two fp32 -> 2 bf16 in one dword
__device__ __forceinline__ u32 pkb(float lo, float hi) {
#if __has_builtin(__builtin_amdgcn_cvt_pk_bf16_f32)
  typedef __bf16 bf16x2 __attribute__((ext_vector_type(2)));
  bf16x2 r = __builtin_amdgcn_cvt_pk_bf16_f32(lo, hi);
  return __builtin_bit_cast(u32, r);
#else
  return __builtin_amdgcn_perm(__builtin_bit_cast(u32, hi),
                               __builtin_bit_cast(u32, lo), 0x07060302u);
#endif
}

__device__ __forceinline__ float fexp2(float x) {
#if __has_builtin(__builtin_amdgcn_exp2f)
  return __builtin_amdgcn_exp2f(x);
#else
  return __builtin_exp2f(x);
#endif
}

// gfx950 cross-lane swaps: odd 16-rows of a <-> even 16-rows of b (16-swap);
// upper 32 lanes of a <-> lower 32 lanes of b (32-swap). Each implements a 2x2
// transpose between one lane bit (4 or 5) and the a/b register-index bit.
__device__ __forceinline__ void pl16swap(u32& a, u32& b) {
  asm("v_permlane16_swap_b32 %0, %1" : "+v"(a), "+v"(b));
}
__device__ __forceinline__ void pl32swap(u32& a, u32& b) {
  asm("v_permlane32_swap_b32 %0, %1" : "+v"(a), "+v"(b));
}

// ---------------- Merged prep: X fp32->bf16 convert + weight transpose/convert --------
// One launch instead of two (neutral-to-slightly-positive, round-6 verified).
__global__ __launch_bounds__(256) void prep(
    const float* __restrict__ q, const float* __restrict__ k, const float* __restrict__ v,
    u16* __restrict__ oq, u16* __restrict__ ok, u16* __restrict__ ov,
    const float* __restrict__ W0, const float* __restrict__ W1, const float* __restrict__ W2,
    u16* __restrict__ O0, u16* __restrict__ O1, u16* __restrict__ O2) {
  const int bid = blockIdx.x;
  if (bid < 12288) {
    const int zz = bid >> 12;            // /4096
    const int bx = bid & 4095;
    const float* X = zz == 0 ? q : zz == 1 ? k : v;
    u16* O = zz == 0 ? oq : zz == 1 ? ok : ov;
    const size_t i = ((size_t)bx * 256 + threadIdx.x) * 8;
    float4 a0 = *(const float4*)(X + i), a1 = *(const float4*)(X + i + 4);
    uint4 p;
    p.x = pkb(a0.x, a0.y); p.y = pkb(a0.z, a0.w);
    p.z = pkb(a1.x, a1.y); p.w = pkb(a1.z, a1.w);
    *(uint4*)(O + i) = p;
  } else {
    const int t = bid - 12288;
    const int zz = t >> 8;
    const int rem = t & 255;
    const int k0 = (rem & 15) * 64, n0 = (rem >> 4) * 64;
    const float* W = zz == 0 ? W0 : zz == 1 ? W1 : W2;
    u16* O = zz == 0 ? O0 : zz == 1 ? O1 : O2;
    const float sc = zz == 0 ? QSCALE : 1.0f;
    __shared__ float tile[64][68];
    const int tid = threadIdx.x;
#pragma unroll
    for (int it = 0; it < 4; ++it) {
      int chunk = tid + it * 256;
      int r = chunk >> 4, c4 = (chunk & 15) * 4;
      *(float4*)&tile[r][c4] = *(const float4*)(W + (size_t)(k0 + r) * DM + n0 + c4);
    }
    __syncthreads();
#pragma unroll
    for (int it = 0; it < 4; ++it) {
      int chunk = tid + it * 256;
      int n = chunk >> 4, k4 = (chunk & 15) * 4;
      ushort4 o;
      o.x = f2bf(tile[k4 + 0][n] * sc);
      o.y = f2bf(tile[k4 + 1][n] * sc);
      o.z = f2bf(tile[k4 + 2][n] * sc);
      o.w = f2bf(tile[k4 + 3][n] * sc);
      *(ushort4*)(O + (size_t)(n0 + n) * DM + k0 + k4) = o;
    }
  }
}

// ---------------- Projection GEMM: BK=32 double-buffered, counted vmcnt ---------------
// Round-6 counters: old drain-structure = 57.2us, MfmaUtil 36% = the m97-structure
// ceiling (900 TF). This version swaps the loop skeleton for the flash-proven pipeline:
//   B1; stage tile t+1 (4 gld); vmcnt(4) [t landed, t+1 in flight]; B2; ds_read; MFMA.
// BK=32 keeps LDS at 32KB (2buf x (A+B) x 128x32x2B) so occupancy stays 3 blk/CU —
// m132's trap (64KB dbuf -> 2 blk -> 874->508) avoided. Fragment math, K accumulation
// order, XCD stripe, and epilogues are identical to round 6 (bitwise-same output).
// LDS swizzle (64B rows, 4 chunks of 16B): slot s of row r holds k-chunk s^((r>>1)&3);
// DMA stays linear (lane l -> row l>>2, slot l&3) with the inverse applied to the
// per-lane GLOBAL k-offset; read at chunk quad^((c16>>1)&3) -> uniform 2-way = free.
__global__ __launch_bounds__(256, 3) void gemm_proj(
    const u16* __restrict__ Xq, const u16* __restrict__ Xk, const u16* __restrict__ Xv,
    const u16* __restrict__ Wq, const u16* __restrict__ Wk, const u16* __restrict__ Wv,
    u16* __restrict__ Oq, u16* __restrict__ Ok, u16* __restrict__ VHt) {
  const int z = blockIdx.y;
  const u16* X = z == 0 ? Xq : z == 1 ? Xk : Xv;    // [M][K] bf16
  const u16* Wt = z == 0 ? Wq : z == 1 ? Wk : Wv;   // [N][K] bf16
  const int xcd = blockIdx.x & 7, j = blockIdx.x >> 3;
  const int n0 = (j & 7) * 128;
  const int m0 = (xcd * 8 + (j >> 3)) * 128;
  __shared__ u16 Al[2][128][32];
  __shared__ u16 Bl[2][128][32];
  const int tid = threadIdx.x, w = tid >> 6, lane = tid & 63;
  const int c16 = lane & 15, quad = lane >> 4;
  const int wm = (w >> 1) * 64, wn = (w & 1) * 64;
  // staging: lane l -> row l>>2 (16 rows/gld), slot l&3; global k-chunk pre-swizzled
  const int srow = lane >> 2;
  const int sk = ((lane & 3) ^ ((lane >> 3) & 3)) * 8;
  const int rswz = (c16 >> 1) & 3;             // read-side row swizzle
  f32x4 acc[4][4] = {};
  const u16* ga = X + (size_t)(m0 + w * 32 + srow) * DM + sk;
  const u16* gb = Wt + (size_t)(n0 + w * 32 + srow) * DM + sk;
  // prologue: stage tile 0 into buf 0 (4 outstanding gld per wave)
  gld_lds16(ga, &Al[0][w * 32][0]);
  gld_lds16(ga + (size_t)16 * DM, &Al[0][w * 32 + 16][0]);
  gld_lds16(gb, &Bl[0][w * 32][0]);
  gld_lds16(gb + (size_t)16 * DM, &Bl[0][w * 32 + 16][0]);
  for (int kt = 0; kt < 32; ++kt) {
    const int buf = kt & 1;
    __builtin_amdgcn_s_barrier();            // B1: buf^1 free (prev tile consumed)
    if (kt < 31) {
      const size_t ko = (size_t)(kt + 1) * 32;
      gld_lds16(ga + ko, &Al[buf ^ 1][w * 32][0]);
      gld_lds16(ga + ko + (size_t)16 * DM, &Al[buf ^ 1][w * 32 + 16][0]);
      gld_lds16(gb + ko, &Bl[buf ^ 1][w * 32][0]);
      gld_lds16(gb + ko + (size_t)16 * DM, &Bl[buf ^ 1][w * 32 + 16][0]);
      asm volatile("s_waitcnt vmcnt(4)" ::: "memory");  // tile kt landed; kt+1 in flight
    } else {
      asm volatile("s_waitcnt vmcnt(0)" ::: "memory");
    }
    __builtin_amdgcn_s_barrier();            // B2: buf[kt] visible to all waves
    bf16x8 af[4], bfr[4];
#pragma unroll
    for (int t = 0; t < 4; ++t)
      af[t] = *(const bf16x8*)&Al[buf][wm + t * 16 + c16][(quad ^ rswz) * 8];
#pragma unroll
    for (int t = 0; t < 4; ++t)
      bfr[t] = *(const bf16x8*)&Bl[buf][wn + t * 16 + c16][(quad ^ rswz) * 8];
#pragma unroll
    for (int mt = 0; mt < 4; ++mt)
#pragma unroll
      for (int nt = 0; nt < 4; ++nt)
        acc[mt][nt] = __builtin_amdgcn_mfma_f32_16x16x32_bf16(af[mt], bfr[nt], acc[mt][nt], 0, 0, 0);
  }
  if (z < 2) {
    u16* O = z == 0 ? Oq : Ok;
#pragma unroll
    for (int mt = 0; mt < 4; ++mt)
#pragma unroll
      for (int nt = 0; nt < 4; ++nt)
#pragma unroll
        for (int r = 0; r < 4; ++r) {
          size_t row = m0 + wm + mt * 16 + quad * 4 + r;
          size_t col = n0 + wn + nt * 16 + c16;
          O[row * DM + col] = f2bf(acc[mt][nt][r]);
        }
  } else {
    // V slice: write transposed VHt[bh][d][t]; the 4 r-values are consecutive t.
#pragma unroll
    for (int mt = 0; mt < 4; ++mt)
#pragma unroll
      for (int nt = 0; nt < 4; ++nt) {
        const int row0 = m0 + wm + mt * 16 + quad * 4;
        const int col = n0 + wn + nt * 16 + c16;
        const int bb = row0 >> 11, t0 = row0 & 2047;
        const int hh = col >> 6, dd = col & 63;
        ushort4 o;
        o.x = f2bf(acc[mt][nt][0]);
        o.y = f2bf(acc[mt][nt][1]);
        o.z = f2bf(acc[mt][nt][2]);
        o.w = f2bf(acc[mt][nt][3]);
        *(ushort4*)(VHt + ((size_t)((bb * 16 + hh) * 64 + dd)) * T + t0) = o;
      }
  }
}

// ---------------- Flash attention + residual, S^T form, permlane P-exchange ----------
// Single 1024-block dispatch (round-6's 2x512 split cost ~20us: halves ran at
// 2 blk/CU and lost the TLP that hides K/V latency — do not split this kernel).
// NO setprio anywhere (rounds 2/3: priority asymmetry desyncs the qb-cohort -> K/V
// falls out of L2, FETCH 52->167MB). v8 ones-MFMA denominators (round 5: -6.2us).
__global__ __launch_bounds__(256, 4) void flash_kernel(
    const u16* __restrict__ QH, const u16* __restrict__ KH, const u16* __restrict__ VHt,
    const float* __restrict__ res, float* __restrict__ out) {
  const int blk = blockIdx.x;
  const int x = blk & 7, g = blk >> 3;
  const int bh = x * 8 + (g & 7);          // XCD x owns heads 8x..8x+7 (K/V ~4MB = L2)
  const int qb = g >> 3;                   // 0..15, 128 q-rows each
  const int b = bh >> 4, h = bh & 15;
  const int tid = threadIdx.x, w = tid >> 6, lane = tid & 63;
  const int c16 = lane & 15, quad = lane >> 4;
  const int swzq = c16 & 7;
  __shared__ u16 Kl[2][64][64];            // [buf][k][d], chunk c of row r at c^(r&7)
  __shared__ u16 Vt[2][64][64];            // [buf][d][k], same swizzle
  const int qbase = qb * 128 + w * 32;
  bf16x8 bq[2][2];                         // B-frags of Q (resident)
#pragma unroll
  for (int qi = 0; qi < 2; ++qi) {
    const u16* qp = QH + (size_t)(b * T + qbase + qi * 16 + c16) * DM + h * 64 + quad * 8;
    bq[qi][0] = *(const bf16x8*)qp;
    bq[qi][1] = *(const bf16x8*)(qp + 32);
  }
  f32x4 acc[2][4] = {};                    // [qi][nt]
  f32x4 accl[2] = {};                      // softmax denominators (ones-trick)
  const u32 one2 = 0x3F803F80u;            // two bf16 1.0
  const uint4 onev = {one2, one2, one2, one2};
  const bf16x8 vone = __builtin_bit_cast(bf16x8, onev);
  const int rk = lane >> 3;
  const int ck8 = ((lane & 7) ^ rk) * 8;
  const u16* kg = KH + (size_t)(b * T) * DM + h * 64 + ck8;
  const u16* vg = VHt + ((size_t)bh * 64 + w * 16 + rk) * T + ck8;
  // prologue: stage tile 0 into buf 0 (4 outstanding vmem per wave)
  {
    const u16* kg0 = kg + (size_t)(w * 16 + rk) * DM;
    gld_lds16(kg0, &Kl[0][w * 16][0]);
    gld_lds16(kg0 + (size_t)8 * DM, &Kl[0][w * 16 + 8][0]);
    gld_lds16(vg, &Vt[0][w * 16][0]);
    gld_lds16(vg + 8 * T, &Vt[0][w * 16 + 8][0]);
  }
  int cur = 0;
  for (int kt = 0; kt < 32; ++kt) {
    // B1: everyone finished reading buf[cur^1] (their ds_reads were MFMA-consumed)
    __builtin_amdgcn_s_barrier();
    if (kt < 31) {
      const u16* kg0 = kg + (size_t)((kt + 1) * 64 + w * 16 + rk) * DM;
      gld_lds16(kg0, &Kl[cur ^ 1][w * 16][0]);
      gld_lds16(kg0 + (size_t)8 * DM, &Kl[cur ^ 1][w * 16 + 8][0]);
      const u16* vg0 = vg + (kt + 1) * 64;
      gld_lds16(vg0, &Vt[cur ^ 1][w * 16][0]);
      gld_lds16(vg0 + (size_t)8 * T, &Vt[cur ^ 1][w * 16 + 8][0]);
      asm volatile("s_waitcnt vmcnt(4)" ::: "memory");  // tile kt landed; kt+1 in flight
    } else {
      asm volatile("s_waitcnt vmcnt(0)" ::: "memory");  // final tile: drain
    }
    // B2: all waves' buf[cur] stages visible
    __builtin_amdgcn_s_barrier();
    // ---- Phase A: S^T = K Q^T, exp2, permlane quad-exchange -> PV A-frags ----
    bf16x8 ap[2][2];
    {
      bf16x8 ak[4][2];
#pragma unroll
      for (int mt = 0; mt < 4; ++mt) {
        const int r = mt * 16 + c16;
        ak[mt][0] = *(const bf16x8*)&Kl[cur][r][(quad ^ swzq) * 8];
        ak[mt][1] = *(const bf16x8*)&Kl[cur][r][((4 + quad) ^ swzq) * 8];
      }
#pragma unroll
      for (int qi = 0; qi < 2; ++qi) {
        u32 d[2][2][2];                    // [mt1][mt0][jd], all indices static
#pragma unroll
        for (int mt = 0; mt < 4; ++mt) {
          f32x4 st = {};
          st = __builtin_amdgcn_mfma_f32_16x16x32_bf16(ak[mt][0], bq[qi][0], st, 0, 0, 0);
          st = __builtin_amdgcn_mfma_f32_16x16x32_bf16(ak[mt][1], bq[qi][1], st, 0, 0, 0);
          const float p0 = fexp2(st[0]), p1 = fexp2(st[1]);
          const float p2 = fexp2(st[2]), p3 = fexp2(st[3]);
          d[mt >> 1][mt & 1][0] = pkb(p0, p1);
          d[mt >> 1][mt & 1][1] = pkb(p2, p3);
        }
        // transpose (lane bit5 <-> reg bit mt0)
        pl32swap(d[0][0][0], d[0][1][0]);
        pl32swap(d[0][0][1], d[0][1][1]);
        pl32swap(d[1][0][0], d[1][1][0]);
        pl32swap(d[1][0][1], d[1][1][1]);
        // transpose (lane bit4 <-> reg bit mt0)
        pl16swap(d[0][0][0], d[0][1][0]);
        pl16swap(d[0][0][1], d[0][1][1]);
        pl16swap(d[1][0][0], d[1][1][0]);
        pl16swap(d[1][0][1], d[1][1][1]);
        // now d[h][e][jd] holds k = 32h + quad*8 + 4e + 2jd (+0,1) for q=qi*16+c16
        uint4 a0 = {d[0][0][0], d[0][0][1], d[0][1][0], d[0][1][1]};
        uint4 a1 = {d[1][0][0], d[1][0][1], d[1][1][0], d[1][1][1]};
        ap[qi][0] = __builtin_bit_cast(bf16x8, a0);
        ap[qi][1] = __builtin_bit_cast(bf16x8, a1);
      }
    }
    // ---- Phase B: O += P V ; denominators += P . 1 (ones-B-frag MFMA) ----
#pragma unroll
    for (int nt = 0; nt < 4; ++nt) {
      const int r = nt * 16 + c16;
      const bf16x8 bv0 = *(const bf16x8*)&Vt[cur][r][(quad ^ swzq) * 8];
      const bf16x8 bv1 = *(const bf16x8*)&Vt[cur][r][((4 + quad) ^ swzq) * 8];
#pragma unroll
      for (int qi = 0; qi < 2; ++qi) {
        acc[qi][nt] = __builtin_amdgcn_mfma_f32_16x16x32_bf16(ap[qi][0], bv0, acc[qi][nt], 0, 0, 0);
        acc[qi][nt] = __builtin_amdgcn_mfma_f32_16x16x32_bf16(ap[qi][1], bv1, acc[qi][nt], 0, 0, 0);
      }
    }
#pragma unroll
    for (int qi = 0; qi < 2; ++qi) {
      accl[qi] = __builtin_amdgcn_mfma_f32_16x16x32_bf16(ap[qi][0], vone, accl[qi], 0, 0, 0);
      accl[qi] = __builtin_amdgcn_mfma_f32_16x16x32_bf16(ap[qi][1], vone, accl[qi], 0, 0, 0);
    }
    cur ^= 1;
  }
  // epilogue: accl[qi][r] = sum_k P[q][k] for q = qbase + qi*16 + quad*4 + r (all c16)
#pragma unroll
  for (int qi = 0; qi < 2; ++qi) {
#pragma unroll
    for (int r = 0; r < 4; ++r) {
      const float inv = 1.0f / accl[qi][r];
      const size_t rowbase = (size_t)(b * T + qbase + qi * 16 + quad * 4 + r) * DM + h * 64;
#pragma unroll
      for (int nt = 0; nt < 4; ++nt) {
        const size_t idx = rowbase + nt * 16 + c16;
        out[idx] = acc[qi][nt][r] * inv + res[idx];
      }
    }
  }
}

extern "C" void kernel_launch(void* const* d_in, const int* in_sizes, int n_in,
                              void* d_out, int out_size, void* d_ws, size_t ws_size,
                              hipStream_t stream) {
  const float* q = (const float*)d_in[0];
  const float* k = (const float*)d_in[1];
  const float* v = (const float*)d_in[2];
  const float* WQ = (const float*)d_in[3];
  const float* WK = (const float*)d_in[4];
  const float* WV = (const float*)d_in[5];
  char* ws = (char*)d_ws;
  const size_t PH = (size_t)8192 * 1024 * 2;   // bf16 activation buffer bytes
  const size_t WT = (size_t)1024 * 1024 * 2;
  // d_out doubles as scratch for 2 of the 3 bf16 X tensors (fully rewritten by flash).
  u16* XqB = (u16*)d_out;
  u16* XkB = (u16*)d_out + (size_t)8192 * 1024;
  u16* XvB = (u16*)(ws);
  u16* WtQ = (u16*)(ws + PH);
  u16* WtK = (u16*)(ws + PH + WT);
  u16* WtV = (u16*)(ws + PH + 2 * WT);
  u16* QH  = (u16*)(ws + PH + 3 * WT);
  u16* KH  = (u16*)(ws + 2 * PH + 3 * WT);
  u16* VHt = (u16*)(ws + 3 * PH + 3 * WT);

  prep<<<dim3(13056), 256, 0, stream>>>(q, k, v, XqB, XkB, XvB,
                                        WQ, WK, WV, WtQ, WtK, WtV);
  gemm_proj<<<dim3(512, 3), 256, 0, stream>>>(XqB, XkB, XvB, WtQ, WtK, WtV, QH, KH, VHt);
  flash_kernel<<<1024, 256, 0, stream>>>(QH, KH, VHt, q, (float*)d_out);
}

// Round 8
// 286.943 us; speedup vs baseline: 1.0295x; 1.0060x over previous
//
#include <hip/hip_runtime.h>
#include <cstdint>
#include <cstddef>

typedef __bf16 bf16x8 __attribute__((ext_vector_type(8)));
typedef float f32x4 __attribute__((ext_vector_type(4)));
typedef unsigned short u16;
typedef unsigned int u32;

static constexpr int T = 2048;
static constexpr int DM = 1024;
// 1/(32*ln2) = log2(e)/32 : folded into W_Q so attention needs only exp2
static constexpr float QSCALE = 0.04508422f;

#define GLOBAL_AS __attribute__((address_space(1)))
#define LDS_AS __attribute__((address_space(3)))

__device__ __forceinline__ void gld_lds16(const u16* g, u16* l) {
  __builtin_amdgcn_global_load_lds((const GLOBAL_AS u32*)g, (LDS_AS u32*)l, 16, 0, 0);
}

__device__ __forceinline__ u16 f2bf(float f) {
  u32 u = __builtin_bit_cast(u32, f);
  u += 0x7fffu + ((u >> 16) & 1u);
  return (u16)(u >> 16);
}

// pack two fp32 -> 2 bf16 in one dword
__device__ __forceinline__ u32 pkb(float lo, float hi) {
#if __has_builtin(__builtin_amdgcn_cvt_pk_bf16_f32)
  typedef __bf16 bf16x2 __attribute__((ext_vector_type(2)));
  bf16x2 r = __builtin_amdgcn_cvt_pk_bf16_f32(lo, hi);
  return __builtin_bit_cast(u32, r);
#else
  return __builtin_amdgcn_perm(__builtin_bit_cast(u32, hi),
                               __builtin_bit_cast(u32, lo), 0x07060302u);
#endif
}

__device__ __forceinline__ float fexp2(float x) {
#if __has_builtin(__builtin_amdgcn_exp2f)
  return __builtin_amdgcn_exp2f(x);
#else
  return __builtin_exp2f(x);
#endif
}

// gfx950 cross-lane swaps: odd 16-rows of a <-> even 16-rows of b (16-swap);
// upper 32 lanes of a <-> lower 32 lanes of b (32-swap). Each implements a 2x2
// transpose between one lane bit (4 or 5) and the a/b register-index bit.
__device__ __forceinline__ void pl16swap(u32& a, u32& b) {
  asm("v_permlane16_swap_b32 %0, %1" : "+v"(a), "+v"(b));
}
__device__ __forceinline__ void pl32swap(u32& a, u32& b) {
  asm("v_permlane32_swap_b32 %0, %1" : "+v"(a), "+v"(b));
}

// ---------------- Merged prep: X fp32->bf16 convert + weight transpose/convert --------
// One launch instead of two. Round-7 ledger exonerated this merge (the round-5
// non-flash regression was gemm's (256,4) scheduling tail, not prep).
__global__ __launch_bounds__(256) void prep(
    const float* __restrict__ q, const float* __restrict__ k, const float* __restrict__ v,
    u16* __restrict__ oq, u16* __restrict__ ok, u16* __restrict__ ov,
    const float* __restrict__ W0, const float* __restrict__ W1, const float* __restrict__ W2,
    u16* __restrict__ O0, u16* __restrict__ O1, u16* __restrict__ O2) {
  const int bid = blockIdx.x;
  if (bid < 12288) {
    const int zz = bid >> 12;            // /4096
    const int bx = bid & 4095;
    const float* X = zz == 0 ? q : zz == 1 ? k : v;
    u16* O = zz == 0 ? oq : zz == 1 ? ok : ov;
    const size_t i = ((size_t)bx * 256 + threadIdx.x) * 8;
    float4 a0 = *(const float4*)(X + i), a1 = *(const float4*)(X + i + 4);
    uint4 p;
    p.x = pkb(a0.x, a0.y); p.y = pkb(a0.z, a0.w);
    p.z = pkb(a1.x, a1.y); p.w = pkb(a1.z, a1.w);
    *(uint4*)(O + i) = p;
  } else {
    const int t = bid - 12288;
    const int zz = t >> 8;
    const int rem = t & 255;
    const int k0 = (rem & 15) * 64, n0 = (rem >> 4) * 64;
    const float* W = zz == 0 ? W0 : zz == 1 ? W1 : W2;
    u16* O = zz == 0 ? O0 : zz == 1 ? O1 : O2;
    const float sc = zz == 0 ? QSCALE : 1.0f;
    __shared__ float tile[64][68];
    const int tid = threadIdx.x;
#pragma unroll
    for (int it = 0; it < 4; ++it) {
      int chunk = tid + it * 256;
      int r = chunk >> 4, c4 = (chunk & 15) * 4;
      *(float4*)&tile[r][c4] = *(const float4*)(W + (size_t)(k0 + r) * DM + n0 + c4);
    }
    __syncthreads();
#pragma unroll
    for (int it = 0; it < 4; ++it) {
      int chunk = tid + it * 256;
      int n = chunk >> 4, k4 = (chunk & 15) * 4;
      ushort4 o;
      o.x = f2bf(tile[k4 + 0][n] * sc);
      o.y = f2bf(tile[k4 + 1][n] * sc);
      o.z = f2bf(tile[k4 + 2][n] * sc);
      o.w = f2bf(tile[k4 + 3][n] * sc);
      *(ushort4*)(O + (size_t)(n0 + n) * DM + k0 + k4) = o;
    }
  }
}

// ---------------- Projection GEMM: BK=64, XCD-stripe swizzle, fused V-transpose -------
// FROZEN at the round-6-measured configuration: 57.2us, 900 TF, MfmaUtil 36% = this
// structure's documented ceiling (m97-band). Four restructure attempts lost:
//   (256,4): grid 1536 @ 4blk/CU = 1.5 scheduling rounds, half-idle tail (+13us)
//   8-phase 256^2 (r2), 128x256 flash-skeleton (r3), BK=32 counted-vmcnt dbuf (r7):
//   all regressed — per-barrier MFMA cluster shrinks faster than sync overhead.
// Do not modify without new counter evidence.
__global__ __launch_bounds__(256, 3) void gemm_proj(
    const u16* __restrict__ Xq, const u16* __restrict__ Xk, const u16* __restrict__ Xv,
    const u16* __restrict__ Wq, const u16* __restrict__ Wk, const u16* __restrict__ Wv,
    u16* __restrict__ Oq, u16* __restrict__ Ok, u16* __restrict__ VHt) {
  const int z = blockIdx.y;
  const u16* X = z == 0 ? Xq : z == 1 ? Xk : Xv;    // [M][K] bf16
  const u16* Wt = z == 0 ? Wq : z == 1 ? Wk : Wv;   // [N][K] bf16
  const int xcd = blockIdx.x & 7, j = blockIdx.x >> 3;
  const int n0 = (j & 7) * 128;
  const int m0 = (xcd * 8 + (j >> 3)) * 128;
  __shared__ u16 Al[128][64];   // unpadded; chunk c of row r stored at c^(r&7)
  __shared__ u16 Bl[128][64];
  const int tid = threadIdx.x, w = tid >> 6, lane = tid & 63;
  const int c16 = lane & 15, quad = lane >> 4;
  const int wm = (w >> 1) * 64, wn = (w & 1) * 64;
  const int rk = lane >> 3;                    // row-in-8 for DMA
  const int ck = ((lane & 7) ^ rk) * 8;        // swizzled global chunk
  const int swz = c16 & 7;
  f32x4 acc[4][4] = {};
  const u16* ga = X + (size_t)(m0 + w * 32 + rk) * DM + ck;
  const u16* gb = Wt + (size_t)(n0 + w * 32 + rk) * DM + ck;
  for (int kk = 0; kk < 1024; kk += 64) {
    __syncthreads();
#pragma unroll
    for (int i = 0; i < 4; ++i) {
      gld_lds16(ga + kk + (size_t)(i * 8) * DM, &Al[w * 32 + i * 8][0]);
      gld_lds16(gb + kk + (size_t)(i * 8) * DM, &Bl[w * 32 + i * 8][0]);
    }
    __syncthreads();
#pragma unroll
    for (int s = 0; s < 2; ++s) {
      bf16x8 af[4], bfr[4];
#pragma unroll
      for (int t = 0; t < 4; ++t) af[t] = *(const bf16x8*)&Al[wm + t * 16 + c16][((quad + 4 * s) ^ swz) * 8];
#pragma unroll
      for (int t = 0; t < 4; ++t) bfr[t] = *(const bf16x8*)&Bl[wn + t * 16 + c16][((quad + 4 * s) ^ swz) * 8];
#pragma unroll
      for (int mt = 0; mt < 4; ++mt)
#pragma unroll
        for (int nt = 0; nt < 4; ++nt)
          acc[mt][nt] = __builtin_amdgcn_mfma_f32_16x16x32_bf16(af[mt], bfr[nt], acc[mt][nt], 0, 0, 0);
    }
  }
  if (z < 2) {
    u16* O = z == 0 ? Oq : Ok;
#pragma unroll
    for (int mt = 0; mt < 4; ++mt)
#pragma unroll
      for (int nt = 0; nt < 4; ++nt)
#pragma unroll
        for (int r = 0; r < 4; ++r) {
          size_t row = m0 + wm + mt * 16 + quad * 4 + r;
          size_t col = n0 + wn + nt * 16 + c16;
          O[row * DM + col] = f2bf(acc[mt][nt][r]);
        }
  } else {
    // V slice: write transposed VHt[bh][d][t]; the 4 r-values are consecutive t.
#pragma unroll
    for (int mt = 0; mt < 4; ++mt)
#pragma unroll
      for (int nt = 0; nt < 4; ++nt) {
        const int row0 = m0 + wm + mt * 16 + quad * 4;
        const int col = n0 + wn + nt * 16 + c16;
        const int bb = row0 >> 11, t0 = row0 & 2047;
        const int hh = col >> 6, dd = col & 63;
        ushort4 o;
        o.x = f2bf(acc[mt][nt][0]);
        o.y = f2bf(acc[mt][nt][1]);
        o.z = f2bf(acc[mt][nt][2]);
        o.w = f2bf(acc[mt][nt][3]);
        *(ushort4*)(VHt + ((size_t)((bb * 16 + hh) * 64 + dd)) * T + t0) = o;
      }
  }
}

// ---------------- Flash attention + residual, S^T form, permlane P-exchange ----------
// FROZEN at the round-7-measured configuration: 80.4us, MfmaUtil 41, VALU 51.
// Single 1024-block dispatch (2x512 split cost ~20us: halves ran at 2 blk/CU).
// NO setprio anywhere (rounds 2/3: priority asymmetry desyncs the qb-cohort -> K/V
// falls out of L2, FETCH 52->167MB). Ones-MFMA denominators (round 5: -6.2us).
__global__ __launch_bounds__(256, 4) void flash_kernel(
    const u16* __restrict__ QH, const u16* __restrict__ KH, const u16* __restrict__ VHt,
    const float* __restrict__ res, float* __restrict__ out) {
  const int blk = blockIdx.x;
  const int x = blk & 7, g = blk >> 3;
  const int bh = x * 8 + (g & 7);          // XCD x owns heads 8x..8x+7 (K/V ~4MB = L2)
  const int qb = g >> 3;                   // 0..15, 128 q-rows each
  const int b = bh >> 4, h = bh & 15;
  const int tid = threadIdx.x, w = tid >> 6, lane = tid & 63;
  const int c16 = lane & 15, quad = lane >> 4;
  const int swzq = c16 & 7;
  __shared__ u16 Kl[2][64][64];            // [buf][k][d], chunk c of row r at c^(r&7)
  __shared__ u16 Vt[2][64][64];            // [buf][d][k], same swizzle
  const int qbase = qb * 128 + w * 32;
  bf16x8 bq[2][2];                         // B-frags of Q (resident)
#pragma unroll
  for (int qi = 0; qi < 2; ++qi) {
    const u16* qp = QH + (size_t)(b * T + qbase + qi * 16 + c16) * DM + h * 64 + quad * 8;
    bq[qi][0] = *(const bf16x8*)qp;
    bq[qi][1] = *(const bf16x8*)(qp + 32);
  }
  f32x4 acc[2][4] = {};                    // [qi][nt]
  f32x4 accl[2] = {};                      // softmax denominators (ones-trick)
  const u32 one2 = 0x3F803F80u;            // two bf16 1.0
  const uint4 onev = {one2, one2, one2, one2};
  const bf16x8 vone = __builtin_bit_cast(bf16x8, onev);
  const int rk = lane >> 3;
  const int ck8 = ((lane & 7) ^ rk) * 8;
  const u16* kg = KH + (size_t)(b * T) * DM + h * 64 + ck8;
  const u16* vg = VHt + ((size_t)bh * 64 + w * 16 + rk) * T + ck8;
  // prologue: stage tile 0 into buf 0 (4 outstanding vmem per wave)
  {
    const u16* kg0 = kg + (size_t)(w * 16 + rk) * DM;
    gld_lds16(kg0, &Kl[0][w * 16][0]);
    gld_lds16(kg0 + (size_t)8 * DM, &Kl[0][w * 16 + 8][0]);
    gld_lds16(vg, &Vt[0][w * 16][0]);
    gld_lds16(vg + 8 * T, &Vt[0][w * 16 + 8][0]);
  }
  int cur = 0;
  for (int kt = 0; kt < 32; ++kt) {
    // B1: everyone finished reading buf[cur^1] (their ds_reads were MFMA-consumed)
    __builtin_amdgcn_s_barrier();
    if (kt < 31) {
      const u16* kg0 = kg + (size_t)((kt + 1) * 64 + w * 16 + rk) * DM;
      gld_lds16(kg0, &Kl[cur ^ 1][w * 16][0]);
      gld_lds16(kg0 + (size_t)8 * DM, &Kl[cur ^ 1][w * 16 + 8][0]);
      const u16* vg0 = vg + (kt + 1) * 64;
      gld_lds16(vg0, &Vt[cur ^ 1][w * 16][0]);
      gld_lds16(vg0 + (size_t)8 * T, &Vt[cur ^ 1][w * 16 + 8][0]);
      asm volatile("s_waitcnt vmcnt(4)" ::: "memory");  // tile kt landed; kt+1 in flight
    } else {
      asm volatile("s_waitcnt vmcnt(0)" ::: "memory");  // final tile: drain
    }
    // B2: all waves' buf[cur] stages visible
    __builtin_amdgcn_s_barrier();
    // ---- Phase A: S^T = K Q^T, exp2, permlane quad-exchange -> PV A-frags ----
    bf16x8 ap[2][2];
    {
      bf16x8 ak[4][2];
#pragma unroll
      for (int mt = 0; mt < 4; ++mt) {
        const int r = mt * 16 + c16;
        ak[mt][0] = *(const bf16x8*)&Kl[cur][r][(quad ^ swzq) * 8];
        ak[mt][1] = *(const bf16x8*)&Kl[cur][r][((4 + quad) ^ swzq) * 8];
      }
#pragma unroll
      for (int qi = 0; qi < 2; ++qi) {
        u32 d[2][2][2];                    // [mt1][mt0][jd], all indices static
#pragma unroll
        for (int mt = 0; mt < 4; ++mt) {
          f32x4 st = {};
          st = __builtin_amdgcn_mfma_f32_16x16x32_bf16(ak[mt][0], bq[qi][0], st, 0, 0, 0);
          st = __builtin_amdgcn_mfma_f32_16x16x32_bf16(ak[mt][1], bq[qi][1], st, 0, 0, 0);
          const float p0 = fexp2(st[0]), p1 = fexp2(st[1]);
          const float p2 = fexp2(st[2]), p3 = fexp2(st[3]);
          d[mt >> 1][mt & 1][0] = pkb(p0, p1);
          d[mt >> 1][mt & 1][1] = pkb(p2, p3);
        }
        // transpose (lane bit5 <-> reg bit mt0)
        pl32swap(d[0][0][0], d[0][1][0]);
        pl32swap(d[0][0][1], d[0][1][1]);
        pl32swap(d[1][0][0], d[1][1][0]);
        pl32swap(d[1][0][1], d[1][1][1]);
        // transpose (lane bit4 <-> reg bit mt0)
        pl16swap(d[0][0][0], d[0][1][0]);
        pl16swap(d[0][0][1], d[0][1][1]);
        pl16swap(d[1][0][0], d[1][1][0]);
        pl16swap(d[1][0][1], d[1][1][1]);
        // now d[h][e][jd] holds k = 32h + quad*8 + 4e + 2jd (+0,1) for q=qi*16+c16
        uint4 a0 = {d[0][0][0], d[0][0][1], d[0][1][0], d[0][1][1]};
        uint4 a1 = {d[1][0][0], d[1][0][1], d[1][1][0], d[1][1][1]};
        ap[qi][0] = __builtin_bit_cast(bf16x8, a0);
        ap[qi][1] = __builtin_bit_cast(bf16x8, a1);
      }
    }
    // ---- Phase B: O += P V ; denominators += P . 1 (ones-B-frag MFMA) ----
#pragma unroll
    for (int nt = 0; nt < 4; ++nt) {
      const int r = nt * 16 + c16;
      const bf16x8 bv0 = *(const bf16x8*)&Vt[cur][r][(quad ^ swzq) * 8];
      const bf16x8 bv1 = *(const bf16x8*)&Vt[cur][r][((4 + quad) ^ swzq) * 8];
#pragma unroll
      for (int qi = 0; qi < 2; ++qi) {
        acc[qi][nt] = __builtin_amdgcn_mfma_f32_16x16x32_bf16(ap[qi][0], bv0, acc[qi][nt], 0, 0, 0);
        acc[qi][nt] = __builtin_amdgcn_mfma_f32_16x16x32_bf16(ap[qi][1], bv1, acc[qi][nt], 0, 0, 0);
      }
    }
#pragma unroll
    for (int qi = 0; qi < 2; ++qi) {
      accl[qi] = __builtin_amdgcn_mfma_f32_16x16x32_bf16(ap[qi][0], vone, accl[qi], 0, 0, 0);
      accl[qi] = __builtin_amdgcn_mfma_f32_16x16x32_bf16(ap[qi][1], vone, accl[qi], 0, 0, 0);
    }
    cur ^= 1;
  }
  // epilogue: accl[qi][r] = sum_k P[q][k] for q = qbase + qi*16 + quad*4 + r (all c16)
#pragma unroll
  for (int qi = 0; qi < 2; ++qi) {
#pragma unroll
    for (int r = 0; r < 4; ++r) {
      const float inv = 1.0f / accl[qi][r];
      const size_t rowbase = (size_t)(b * T + qbase + qi * 16 + quad * 4 + r) * DM + h * 64;
#pragma unroll
      for (int nt = 0; nt < 4; ++nt) {
        const size_t idx = rowbase + nt * 16 + c16;
        out[idx] = acc[qi][nt][r] * inv + res[idx];
      }
    }
  }
}

extern "C" void kernel_launch(void* const* d_in, const int* in_sizes, int n_in,
                              void* d_out, int out_size, void* d_ws, size_t ws_size,
                              hipStream_t stream) {
  const float* q = (const float*)d_in[0];
  const float* k = (const float*)d_in[1];
  const float* v = (const float*)d_in[2];
  const float* WQ = (const float*)d_in[3];
  const float* WK = (const float*)d_in[4];
  const float* WV = (const float*)d_in[5];
  char* ws = (char*)d_ws;
  const size_t PH = (size_t)8192 * 1024 * 2;   // bf16 activation buffer bytes
  const size_t WT = (size_t)1024 * 1024 * 2;
  // d_out doubles as scratch for 2 of the 3 bf16 X tensors (fully rewritten by flash).
  u16* XqB = (u16*)d_out;
  u16* XkB = (u16*)d_out + (size_t)8192 * 1024;
  u16* XvB = (u16*)(ws);
  u16* WtQ = (u16*)(ws + PH);
  u16* WtK = (u16*)(ws + PH + WT);
  u16* WtV = (u16*)(ws + PH + 2 * WT);
  u16* QH  = (u16*)(ws + PH + 3 * WT);
  u16* KH  = (u16*)(ws + 2 * PH + 3 * WT);
  u16* VHt = (u16*)(ws + 3 * PH + 3 * WT);

  prep<<<dim3(13056), 256, 0, stream>>>(q, k, v, XqB, XkB, XvB,
                                        WQ, WK, WV, WtQ, WtK, WtV);
  gemm_proj<<<dim3(512, 3), 256, 0, stream>>>(XqB, XkB, XvB, WtQ, WtK, WtV, QH, KH, VHt);
  flash_kernel<<<1024, 256, 0, stream>>>(QH, KH, VHt, q, (float*)d_out);
}

// Round 9
// 277.637 us; speedup vs baseline: 1.0640x; 1.0335x over previous
//
#include <hip/hip_runtime.h>
#include <cstdint>
#include <cstddef>

typedef __bf16 bf16x8 __attribute__((ext_vector_type(8)));
typedef float f32x4 __attribute__((ext_vector_type(4)));
typedef unsigned short u16;
typedef unsigned int u32;

static constexpr int T = 2048;
static constexpr int DM = 1024;
// 1/(32*ln2) = log2(e)/32 : folded into W_Q so attention needs only exp2
static constexpr float QSCALE = 0.04508422f;

#define GLOBAL_AS __attribute__((address_space(1)))
#define LDS_AS __attribute__((address_space(3)))

__device__ __forceinline__ void gld_lds16(const u16* g, u16* l) {
  __builtin_amdgcn_global_load_lds((const GLOBAL_AS u32*)g, (LDS_AS u32*)l, 16, 0, 0);
}

__device__ __forceinline__ u16 f2bf(float f) {
  u32 u = __builtin_bit_cast(u32, f);
  u += 0x7fffu + ((u >> 16) & 1u);
  return (u16)(u >> 16);
}

// pack two fp32 -> 2 bf16 in one dword
__device__ __forceinline__ u32 pkb(float lo, float hi) {
#if __has_builtin(__builtin_amdgcn_cvt_pk_bf16_f32)
  typedef __bf16 bf16x2 __attribute__((ext_vector_type(2)));
  bf16x2 r = __builtin_amdgcn_cvt_pk_bf16_f32(lo, hi);
  return __builtin_bit_cast(u32, r);
#else
  return __builtin_amdgcn_perm(__builtin_bit_cast(u32, hi),
                               __builtin_bit_cast(u32, lo), 0x07060302u);
#endif
}

__device__ __forceinline__ float fexp2(float x) {
#if __has_builtin(__builtin_amdgcn_exp2f)
  return __builtin_amdgcn_exp2f(x);
#else
  return __builtin_exp2f(x);
#endif
}

// gfx950 cross-lane swaps: odd 16-rows of a <-> even 16-rows of b (16-swap);
// upper 32 lanes of a <-> lower 32 lanes of b (32-swap). Each implements a 2x2
// transpose between one lane bit (4 or 5) and the a/b register-index bit.
__device__ __forceinline__ void pl16swap(u32& a, u32& b) {
  asm("v_permlane16_swap_b32 %0, %1" : "+v"(a), "+v"(b));
}
__device__ __forceinline__ void pl32swap(u32& a, u32& b) {
  asm("v_permlane32_swap_b32 %0, %1" : "+v"(a), "+v"(b));
}

// ---------------- X fp32 -> bf16 convert (once) ---------------------------------------
// SEPARATE kernel (not merged with wt): the R4-vs-{R5,R7,R8} ledger pins ~+12us on the
// merged-prep variant — the merged kernel inherits the wt branch's LDS/VGPR footprint,
// costing the 12288 BW-bound xcvt blocks their occupancy. Keep these two split.
__global__ __launch_bounds__(256) void xcvt(
    const float* __restrict__ q, const float* __restrict__ k, const float* __restrict__ v,
    u16* __restrict__ oq, u16* __restrict__ ok, u16* __restrict__ ov) {
  const float* X = blockIdx.y == 0 ? q : blockIdx.y == 1 ? k : v;
  u16* O = blockIdx.y == 0 ? oq : blockIdx.y == 1 ? ok : ov;
  const size_t i = ((size_t)blockIdx.x * 256 + threadIdx.x) * 8;
  float4 a0 = *(const float4*)(X + i), a1 = *(const float4*)(X + i + 4);
  uint4 p;
  p.x = pkb(a0.x, a0.y); p.y = pkb(a0.z, a0.w);
  p.z = pkb(a1.x, a1.y); p.w = pkb(a1.z, a1.w);
  *(uint4*)(O + i) = p;
}

// ---------------- Weight transpose + convert: Wt[n][k] bf16 from W[k][n] fp32 --------
__global__ __launch_bounds__(256) void wt_kernel(
    const float* __restrict__ W0, const float* __restrict__ W1, const float* __restrict__ W2,
    u16* __restrict__ O0, u16* __restrict__ O1, u16* __restrict__ O2) {
  const float* W = blockIdx.z == 0 ? W0 : blockIdx.z == 1 ? W1 : W2;
  u16* O = blockIdx.z == 0 ? O0 : blockIdx.z == 1 ? O1 : O2;
  const float sc = blockIdx.z == 0 ? QSCALE : 1.0f;
  const int k0 = blockIdx.x * 64, n0 = blockIdx.y * 64;
  __shared__ float tile[64][68];
  const int tid = threadIdx.x;
#pragma unroll
  for (int it = 0; it < 4; ++it) {
    int chunk = tid + it * 256;
    int r = chunk >> 4, c4 = (chunk & 15) * 4;
    *(float4*)&tile[r][c4] = *(const float4*)(W + (size_t)(k0 + r) * DM + n0 + c4);
  }
  __syncthreads();
#pragma unroll
  for (int it = 0; it < 4; ++it) {
    int chunk = tid + it * 256;
    int n = chunk >> 4, k4 = (chunk & 15) * 4;
    ushort4 o;
    o.x = f2bf(tile[k4 + 0][n] * sc);
    o.y = f2bf(tile[k4 + 1][n] * sc);
    o.z = f2bf(tile[k4 + 2][n] * sc);
    o.w = f2bf(tile[k4 + 3][n] * sc);
    *(ushort4*)(O + (size_t)(n0 + n) * DM + k0 + k4) = o;
  }
}

// ---------------- Projection GEMM: BK=64, XCD-stripe swizzle, fused V-transpose -------
// FROZEN at the round-6-measured configuration: 57.2us, 900 TF, MfmaUtil 36% = this
// structure's documented ceiling (m97-band). Restructure attempts that lost:
//   8-phase 256^2 (r2), 128x256 flash-skeleton (r3), BK=32 counted-vmcnt dbuf (r7) —
//   per-barrier MFMA cluster shrinks faster than sync overhead.
// ((256,4) is exonerated by the R5-vs-R8 ledger but brings no gain; keep (256,3).)
// Do not modify without new counter evidence.
__global__ __launch_bounds__(256, 3) void gemm_proj(
    const u16* __restrict__ Xq, const u16* __restrict__ Xk, const u16* __restrict__ Xv,
    const u16* __restrict__ Wq, const u16* __restrict__ Wk, const u16* __restrict__ Wv,
    u16* __restrict__ Oq, u16* __restrict__ Ok, u16* __restrict__ VHt) {
  const int z = blockIdx.y;
  const u16* X = z == 0 ? Xq : z == 1 ? Xk : Xv;    // [M][K] bf16
  const u16* Wt = z == 0 ? Wq : z == 1 ? Wk : Wv;   // [N][K] bf16
  const int xcd = blockIdx.x & 7, j = blockIdx.x >> 3;
  const int n0 = (j & 7) * 128;
  const int m0 = (xcd * 8 + (j >> 3)) * 128;
  __shared__ u16 Al[128][64];   // unpadded; chunk c of row r stored at c^(r&7)
  __shared__ u16 Bl[128][64];
  const int tid = threadIdx.x, w = tid >> 6, lane = tid & 63;
  const int c16 = lane & 15, quad = lane >> 4;
  const int wm = (w >> 1) * 64, wn = (w & 1) * 64;
  const int rk = lane >> 3;                    // row-in-8 for DMA
  const int ck = ((lane & 7) ^ rk) * 8;        // swizzled global chunk
  const int swz = c16 & 7;
  f32x4 acc[4][4] = {};
  const u16* ga = X + (size_t)(m0 + w * 32 + rk) * DM + ck;
  const u16* gb = Wt + (size_t)(n0 + w * 32 + rk) * DM + ck;
  for (int kk = 0; kk < 1024; kk += 64) {
    __syncthreads();
#pragma unroll
    for (int i = 0; i < 4; ++i) {
      gld_lds16(ga + kk + (size_t)(i * 8) * DM, &Al[w * 32 + i * 8][0]);
      gld_lds16(gb + kk + (size_t)(i * 8) * DM, &Bl[w * 32 + i * 8][0]);
    }
    __syncthreads();
#pragma unroll
    for (int s = 0; s < 2; ++s) {
      bf16x8 af[4], bfr[4];
#pragma unroll
      for (int t = 0; t < 4; ++t) af[t] = *(const bf16x8*)&Al[wm + t * 16 + c16][((quad + 4 * s) ^ swz) * 8];
#pragma unroll
      for (int t = 0; t < 4; ++t) bfr[t] = *(const bf16x8*)&Bl[wn + t * 16 + c16][((quad + 4 * s) ^ swz) * 8];
#pragma unroll
      for (int mt = 0; mt < 4; ++mt)
#pragma unroll
        for (int nt = 0; nt < 4; ++nt)
          acc[mt][nt] = __builtin_amdgcn_mfma_f32_16x16x32_bf16(af[mt], bfr[nt], acc[mt][nt], 0, 0, 0);
    }
  }
  if (z < 2) {
    u16* O = z == 0 ? Oq : Ok;
#pragma unroll
    for (int mt = 0; mt < 4; ++mt)
#pragma unroll
      for (int nt = 0; nt < 4; ++nt)
#pragma unroll
        for (int r = 0; r < 4; ++r) {
          size_t row = m0 + wm + mt * 16 + quad * 4 + r;
          size_t col = n0 + wn + nt * 16 + c16;
          O[row * DM + col] = f2bf(acc[mt][nt][r]);
        }
  } else {
    // V slice: write transposed VHt[bh][d][t]; the 4 r-values are consecutive t.
#pragma unroll
    for (int mt = 0; mt < 4; ++mt)
#pragma unroll
      for (int nt = 0; nt < 4; ++nt) {
        const int row0 = m0 + wm + mt * 16 + quad * 4;
        const int col = n0 + wn + nt * 16 + c16;
        const int bb = row0 >> 11, t0 = row0 & 2047;
        const int hh = col >> 6, dd = col & 63;
        ushort4 o;
        o.x = f2bf(acc[mt][nt][0]);
        o.y = f2bf(acc[mt][nt][1]);
        o.z = f2bf(acc[mt][nt][2]);
        o.w = f2bf(acc[mt][nt][3]);
        *(ushort4*)(VHt + ((size_t)((bb * 16 + hh) * 64 + dd)) * T + t0) = o;
      }
  }
}

// ---------------- Flash attention + residual, S^T form, permlane P-exchange ----------
// FROZEN at the round-7/8-measured configuration: ~81us, MfmaUtil ~41, VALU ~50.
// Single 1024-block dispatch (2x512 split cost ~20us: halves ran at 2 blk/CU).
// NO setprio anywhere (rounds 2/3: priority asymmetry desyncs the qb-cohort -> K/V
// falls out of L2, FETCH 52->167MB). Ones-MFMA denominators (round 5: -6.2us).
__global__ __launch_bounds__(256, 4) void flash_kernel(
    const u16* __restrict__ QH, const u16* __restrict__ KH, const u16* __restrict__ VHt,
    const float* __restrict__ res, float* __restrict__ out) {
  const int blk = blockIdx.x;
  const int x = blk & 7, g = blk >> 3;
  const int bh = x * 8 + (g & 7);          // XCD x owns heads 8x..8x+7 (K/V ~4MB = L2)
  const int qb = g >> 3;                   // 0..15, 128 q-rows each
  const int b = bh >> 4, h = bh & 15;
  const int tid = threadIdx.x, w = tid >> 6, lane = tid & 63;
  const int c16 = lane & 15, quad = lane >> 4;
  const int swzq = c16 & 7;
  __shared__ u16 Kl[2][64][64];            // [buf][k][d], chunk c of row r at c^(r&7)
  __shared__ u16 Vt[2][64][64];            // [buf][d][k], same swizzle
  const int qbase = qb * 128 + w * 32;
  bf16x8 bq[2][2];                         // B-frags of Q (resident)
#pragma unroll
  for (int qi = 0; qi < 2; ++qi) {
    const u16* qp = QH + (size_t)(b * T + qbase + qi * 16 + c16) * DM + h * 64 + quad * 8;
    bq[qi][0] = *(const bf16x8*)qp;
    bq[qi][1] = *(const bf16x8*)(qp + 32);
  }
  f32x4 acc[2][4] = {};                    // [qi][nt]
  f32x4 accl[2] = {};                      // softmax denominators (ones-trick)
  const u32 one2 = 0x3F803F80u;            // two bf16 1.0
  const uint4 onev = {one2, one2, one2, one2};
  const bf16x8 vone = __builtin_bit_cast(bf16x8, onev);
  const int rk = lane >> 3;
  const int ck8 = ((lane & 7) ^ rk) * 8;
  const u16* kg = KH + (size_t)(b * T) * DM + h * 64 + ck8;
  const u16* vg = VHt + ((size_t)bh * 64 + w * 16 + rk) * T + ck8;
  // prologue: stage tile 0 into buf 0 (4 outstanding vmem per wave)
  {
    const u16* kg0 = kg + (size_t)(w * 16 + rk) * DM;
    gld_lds16(kg0, &Kl[0][w * 16][0]);
    gld_lds16(kg0 + (size_t)8 * DM, &Kl[0][w * 16 + 8][0]);
    gld_lds16(vg, &Vt[0][w * 16][0]);
    gld_lds16(vg + 8 * T, &Vt[0][w * 16 + 8][0]);
  }
  int cur = 0;
  for (int kt = 0; kt < 32; ++kt) {
    // B1: everyone finished reading buf[cur^1] (their ds_reads were MFMA-consumed)
    __builtin_amdgcn_s_barrier();
    if (kt < 31) {
      const u16* kg0 = kg + (size_t)((kt + 1) * 64 + w * 16 + rk) * DM;
      gld_lds16(kg0, &Kl[cur ^ 1][w * 16][0]);
      gld_lds16(kg0 + (size_t)8 * DM, &Kl[cur ^ 1][w * 16 + 8][0]);
      const u16* vg0 = vg + (kt + 1) * 64;
      gld_lds16(vg0, &Vt[cur ^ 1][w * 16][0]);
      gld_lds16(vg0 + (size_t)8 * T, &Vt[cur ^ 1][w * 16 + 8][0]);
      asm volatile("s_waitcnt vmcnt(4)" ::: "memory");  // tile kt landed; kt+1 in flight
    } else {
      asm volatile("s_waitcnt vmcnt(0)" ::: "memory");  // final tile: drain
    }
    // B2: all waves' buf[cur] stages visible
    __builtin_amdgcn_s_barrier();
    // ---- Phase A: S^T = K Q^T, exp2, permlane quad-exchange -> PV A-frags ----
    bf16x8 ap[2][2];
    {
      bf16x8 ak[4][2];
#pragma unroll
      for (int mt = 0; mt < 4; ++mt) {
        const int r = mt * 16 + c16;
        ak[mt][0] = *(const bf16x8*)&Kl[cur][r][(quad ^ swzq) * 8];
        ak[mt][1] = *(const bf16x8*)&Kl[cur][r][((4 + quad) ^ swzq) * 8];
      }
#pragma unroll
      for (int qi = 0; qi < 2; ++qi) {
        u32 d[2][2][2];                    // [mt1][mt0][jd], all indices static
#pragma unroll
        for (int mt = 0; mt < 4; ++mt) {
          f32x4 st = {};
          st = __builtin_amdgcn_mfma_f32_16x16x32_bf16(ak[mt][0], bq[qi][0], st, 0, 0, 0);
          st = __builtin_amdgcn_mfma_f32_16x16x32_bf16(ak[mt][1], bq[qi][1], st, 0, 0, 0);
          const float p0 = fexp2(st[0]), p1 = fexp2(st[1]);
          const float p2 = fexp2(st[2]), p3 = fexp2(st[3]);
          d[mt >> 1][mt & 1][0] = pkb(p0, p1);
          d[mt >> 1][mt & 1][1] = pkb(p2, p3);
        }
        // transpose (lane bit5 <-> reg bit mt0)
        pl32swap(d[0][0][0], d[0][1][0]);
        pl32swap(d[0][0][1], d[0][1][1]);
        pl32swap(d[1][0][0], d[1][1][0]);
        pl32swap(d[1][0][1], d[1][1][1]);
        // transpose (lane bit4 <-> reg bit mt0)
        pl16swap(d[0][0][0], d[0][1][0]);
        pl16swap(d[0][0][1], d[0][1][1]);
        pl16swap(d[1][0][0], d[1][1][0]);
        pl16swap(d[1][0][1], d[1][1][1]);
        // now d[h][e][jd] holds k = 32h + quad*8 + 4e + 2jd (+0,1) for q=qi*16+c16
        uint4 a0 = {d[0][0][0], d[0][0][1], d[0][1][0], d[0][1][1]};
        uint4 a1 = {d[1][0][0], d[1][0][1], d[1][1][0], d[1][1][1]};
        ap[qi][0] = __builtin_bit_cast(bf16x8, a0);
        ap[qi][1] = __builtin_bit_cast(bf16x8, a1);
      }
    }
    // ---- Phase B: O += P V ; denominators += P . 1 (ones-B-frag MFMA) ----
#pragma unroll
    for (int nt = 0; nt < 4; ++nt) {
      const int r = nt * 16 + c16;
      const bf16x8 bv0 = *(const bf16x8*)&Vt[cur][r][(quad ^ swzq) * 8];
      const bf16x8 bv1 = *(const bf16x8*)&Vt[cur][r][((4 + quad) ^ swzq) * 8];
#pragma unroll
      for (int qi = 0; qi < 2; ++qi) {
        acc[qi][nt] = __builtin_amdgcn_mfma_f32_16x16x32_bf16(ap[qi][0], bv0, acc[qi][nt], 0, 0, 0);
        acc[qi][nt] = __builtin_amdgcn_mfma_f32_16x16x32_bf16(ap[qi][1], bv1, acc[qi][nt], 0, 0, 0);
      }
    }
#pragma unroll
    for (int qi = 0; qi < 2; ++qi) {
      accl[qi] = __builtin_amdgcn_mfma_f32_16x16x32_bf16(ap[qi][0], vone, accl[qi], 0, 0, 0);
      accl[qi] = __builtin_amdgcn_mfma_f32_16x16x32_bf16(ap[qi][1], vone, accl[qi], 0, 0, 0);
    }
    cur ^= 1;
  }
  // epilogue: accl[qi][r] = sum_k P[q][k] for q = qbase + qi*16 + quad*4 + r (all c16)
#pragma unroll
  for (int qi = 0; qi < 2; ++qi) {
#pragma unroll
    for (int r = 0; r < 4; ++r) {
      const float inv = 1.0f / accl[qi][r];
      const size_t rowbase = (size_t)(b * T + qbase + qi * 16 + quad * 4 + r) * DM + h * 64;
#pragma unroll
      for (int nt = 0; nt < 4; ++nt) {
        const size_t idx = rowbase + nt * 16 + c16;
        out[idx] = acc[qi][nt][r] * inv + res[idx];
      }
    }
  }
}

extern "C" void kernel_launch(void* const* d_in, const int* in_sizes, int n_in,
                              void* d_out, int out_size, void* d_ws, size_t ws_size,
                              hipStream_t stream) {
  const float* q = (const float*)d_in[0];
  const float* k = (const float*)d_in[1];
  const float* v = (const float*)d_in[2];
  const float* WQ = (const float*)d_in[3];
  const float* WK = (const float*)d_in[4];
  const float* WV = (const float*)d_in[5];
  char* ws = (char*)d_ws;
  const size_t PH = (size_t)8192 * 1024 * 2;   // bf16 activation buffer bytes
  const size_t WT = (size_t)1024 * 1024 * 2;
  // d_out doubles as scratch for 2 of the 3 bf16 X tensors (fully rewritten by flash).
  u16* XqB = (u16*)d_out;
  u16* XkB = (u16*)d_out + (size_t)8192 * 1024;
  u16* XvB = (u16*)(ws);
  u16* WtQ = (u16*)(ws + PH);
  u16* WtK = (u16*)(ws + PH + WT);
  u16* WtV = (u16*)(ws + PH + 2 * WT);
  u16* QH  = (u16*)(ws + PH + 3 * WT);
  u16* KH  = (u16*)(ws + 2 * PH + 3 * WT);
  u16* VHt = (u16*)(ws + 3 * PH + 3 * WT);

  xcvt<<<dim3(4096, 3), 256, 0, stream>>>(q, k, v, XqB, XkB, XvB);
  wt_kernel<<<dim3(16, 16, 3), 256, 0, stream>>>(WQ, WK, WV, WtQ, WtK, WtV);
  gemm_proj<<<dim3(512, 3), 256, 0, stream>>>(XqB, XkB, XvB, WtQ, WtK, WtV, QH, KH, VHt);
  flash_kernel<<<1024, 256, 0, stream>>>(QH, KH, VHt, q, (float*)d_out);
}